// Round 1
// baseline (616.161 us; speedup 1.0000x reference)
//
#include <hip/hip_runtime.h>
#include <hip/hip_bf16.h>

#define N 8192
#define FIN 256
#define HD 256
#define LEAKY 0.2f

typedef short sh8 __attribute__((ext_vector_type(8)));   // bf16x8 MFMA fragment
typedef float f32x4 __attribute__((ext_vector_type(4)));
typedef int   i32x4 __attribute__((ext_vector_type(4)));

__device__ __forceinline__ int pack2bf(float a, float b){
  __hip_bfloat162 t = __float22bfloat162_rn(make_float2(a, b));
  union { __hip_bfloat162 h; int i; } u;
  u.h = t;
  return u.i;
}

// ---------------- K0: W (256x256 f32, [k][c]) -> Wt (bf16, [c][k]) ----------------
__global__ void k_wt(const float* __restrict__ W, __hip_bfloat16* __restrict__ Wt){
  __shared__ float t[16][17];
  int tx = threadIdx.x, ty = threadIdx.y;
  int bx = blockIdx.x*16, by = blockIdx.y*16;
  t[ty][tx] = W[(by+ty)*HD + (bx+tx)];
  __syncthreads();
  Wt[(bx+ty)*FIN + (by+tx)] = __float2bfloat16(t[tx][ty]);
}

// ---------------- K1: h_t[c][n] = sum_k W[k][c] * x[n][k]  (bf16 out) --------------
// Also fused: score_l/score_r per (head,n) and exp factors El,El2,Er,Er2.
// sc layout (each 4*N floats, head-major): [sl, sr, El, El2, Er, Er2]
__global__ __launch_bounds__(256, 2) void k_h(
    const float* __restrict__ x, const __hip_bfloat16* __restrict__ Wt,
    const float* __restrict__ a_l, const float* __restrict__ a_r,
    __hip_bfloat16* __restrict__ ht, float* __restrict__ sc)
{
  const int lane = threadIdx.x & 63;
  const int w = threadIdx.x >> 6;      // c-group == head
  const int r0 = lane & 15, q = lane >> 4;
  const int c0 = w*64;
  const int n0 = blockIdx.x*32;

  f32x4 acc[4][2];
  #pragma unroll
  for (int m = 0; m < 4; ++m)
    #pragma unroll
    for (int nt = 0; nt < 2; ++nt)
      acc[m][nt] = (f32x4){0.f, 0.f, 0.f, 0.f};

  for (int kb = 0; kb < 8; ++kb){
    const int k = kb*32 + q*8;
    sh8 af[4];
    #pragma unroll
    for (int m = 0; m < 4; ++m)
      af[m] = *(const sh8*)(Wt + (c0 + m*16 + r0)*FIN + k);
    #pragma unroll
    for (int nt = 0; nt < 2; ++nt){
      const float* xp = x + (n0 + nt*16 + r0)*FIN + k;
      f32x4 xl = *(const f32x4*)xp;
      f32x4 xh = *(const f32x4*)(xp + 4);
      union { sh8 s; int i[4]; } bx;
      bx.i[0] = pack2bf(xl[0], xl[1]);
      bx.i[1] = pack2bf(xl[2], xl[3]);
      bx.i[2] = pack2bf(xh[0], xh[1]);
      bx.i[3] = pack2bf(xh[2], xh[3]);
      #pragma unroll
      for (int m = 0; m < 4; ++m)
        acc[m][nt] = __builtin_amdgcn_mfma_f32_16x16x32_bf16(af[m], bx.s, acc[m][nt], 0, 0, 0);
    }
  }

  // epilogue: store h_t (bf16) + fused scores
  float pl[2] = {0.f, 0.f}, pr[2] = {0.f, 0.f};
  #pragma unroll
  for (int m = 0; m < 4; ++m){
    #pragma unroll
    for (int reg = 0; reg < 4; ++reg){
      const int c = c0 + m*16 + q*4 + reg;      // C row = q*4+reg
      const float alv = a_l[c], arv = a_r[c];
      #pragma unroll
      for (int nt = 0; nt < 2; ++nt){
        float v = acc[m][nt][reg];
        ht[(size_t)c*N + (n0 + nt*16 + r0)] = __float2bfloat16(v);  // C col = r0
        pl[nt] += v*alv;
        pr[nt] += v*arv;
      }
    }
  }
  #pragma unroll
  for (int nt = 0; nt < 2; ++nt){
    pl[nt] += __shfl_xor(pl[nt], 16); pl[nt] += __shfl_xor(pl[nt], 32);
    pr[nt] += __shfl_xor(pr[nt], 16); pr[nt] += __shfl_xor(pr[nt], 32);
  }
  if (lane < 16){
    float* slp  = sc;
    float* srp  = sc + 4*N;
    float* Elp  = sc + 8*N;
    float* El2p = sc + 12*N;
    float* Erp  = sc + 16*N;
    float* Er2p = sc + 20*N;
    #pragma unroll
    for (int nt = 0; nt < 2; ++nt){
      const int n = n0 + nt*16 + r0;
      const float l = pl[nt], r = pr[nt];
      slp [w*N + n] = l;
      srp [w*N + n] = r;
      Elp [w*N + n] = __expf(l);
      El2p[w*N + n] = __expf(LEAKY*l);
      Erp [w*N + n] = __expf(r);
      Er2p[w*N + n] = __expf(LEAKY*r);
    }
  }
}

// ---------------- K2: masked-softmax numerator/denominator partials ----------------
// grid 512: block b -> i-tile (b>>2)*64, j-quarter (b&3)*2048. 4 waves = 4 heads.
// part[jq][i][c] fp32 ; zpart[jq][h][i] fp32
__global__ __launch_bounds__(256, 2) void k_attn(
    const int* __restrict__ adj, const __hip_bfloat16* __restrict__ ht,
    const float* __restrict__ sc, float* __restrict__ part, float* __restrict__ zpart)
{
  const int b = blockIdx.x;
  const int iblk = b >> 2, jq = b & 3;
  const int lane = threadIdx.x & 63;
  const int h = threadIdx.x >> 6;
  const int r0 = lane & 15, q = lane >> 4;
  const int i0 = iblk * 64;

  const float* slp  = sc + h*N;
  const float* srp  = sc + 4*N  + h*N;
  const float* Elp  = sc + 8*N  + h*N;
  const float* El2p = sc + 12*N + h*N;
  const float* Erp  = sc + 16*N + h*N;
  const float* Er2p = sc + 20*N + h*N;

  float tau[4], el[4], el2[4];
  int rowm[4];
  #pragma unroll
  for (int m = 0; m < 4; ++m){
    rowm[m] = i0 + m*16 + r0;              // A-operand row for this lane
    tau[m] = -slp[rowm[m]];                // t>0  <=>  sr[j] > -sl[i]
    el[m]  = Elp[rowm[m]];
    el2[m] = El2p[rowm[m]];
  }

  f32x4 acc[4][4];
  #pragma unroll
  for (int m = 0; m < 4; ++m)
    #pragma unroll
    for (int d = 0; d < 4; ++d)
      acc[m][d] = (f32x4){0.f, 0.f, 0.f, 0.f};
  float z[4] = {0.f, 0.f, 0.f, 0.f};

  const __hip_bfloat16* htb = ht + (size_t)(h*64 + r0)*N;
  const int jbase = jq*2048;

  // one-iteration-ahead prefetch of the adj stream (HBM ~900cy latency)
  i32x4 ca[4][2], na[4][2];
  {
    const int jl0 = jbase + q*8;
    #pragma unroll
    for (int m = 0; m < 4; ++m){
      const i32x4* ap = (const i32x4*)(adj + (size_t)rowm[m]*N + jl0);
      ca[m][0] = __builtin_nontemporal_load(ap);
      ca[m][1] = __builtin_nontemporal_load(ap + 1);
    }
  }

  for (int t = 0; t < 64; ++t){
    const int j0 = jbase + t*32;
    const int jl = j0 + q*8;              // this lane's j start (k = q*8+e)

    {
      const int tn = (t < 63) ? (t + 1) : t;
      const int jln = jbase + tn*32 + q*8;
      #pragma unroll
      for (int m = 0; m < 4; ++m){
        const i32x4* ap = (const i32x4*)(adj + (size_t)rowm[m]*N + jln);
        na[m][0] = __builtin_nontemporal_load(ap);
        na[m][1] = __builtin_nontemporal_load(ap + 1);
      }
    }

    f32x4 srl = *(const f32x4*)(srp  + jl);
    f32x4 srh = *(const f32x4*)(srp  + jl + 4);
    f32x4 erl = *(const f32x4*)(Erp  + jl);
    f32x4 erh = *(const f32x4*)(Erp  + jl + 4);
    f32x4 e2l = *(const f32x4*)(Er2p + jl);
    f32x4 e2h = *(const f32x4*)(Er2p + jl + 4);
    float srv[8] = {srl[0],srl[1],srl[2],srl[3],srh[0],srh[1],srh[2],srh[3]};
    float erv[8] = {erl[0],erl[1],erl[2],erl[3],erh[0],erh[1],erh[2],erh[3]};
    float e2v[8] = {e2l[0],e2l[1],e2l[2],e2l[3],e2h[0],e2h[1],e2h[2],e2h[3]};

    sh8 bf[4];
    #pragma unroll
    for (int d = 0; d < 4; ++d)
      bf[d] = *(const sh8*)(htb + (size_t)(d*16)*N + jl);  // B[k][n]: n=r0(col), k consecutive

    #pragma unroll
    for (int m = 0; m < 4; ++m){
      int av[8];
      av[0]=ca[m][0][0]; av[1]=ca[m][0][1]; av[2]=ca[m][0][2]; av[3]=ca[m][0][3];
      av[4]=ca[m][1][0]; av[5]=ca[m][1][1]; av[6]=ca[m][1][2]; av[7]=ca[m][1][3];
      float wv[8];
      const bool dg = (j0 == i0 + (m >> 1)*32);   // wave-uniform: diagonal k-block for this m
      if (!dg){
        #pragma unroll
        for (int e = 0; e < 8; ++e){
          bool pos = srv[e] > tau[m];
          float wx = (pos ? el[m] : el2[m]) * (pos ? erv[e] : e2v[e]);
          wv[e] = (av[e] != 0) ? wx : 0.0f;
        }
      } else {
        #pragma unroll
        for (int e = 0; e < 8; ++e){
          bool pos = srv[e] > tau[m];
          float wx = (pos ? el[m] : el2[m]) * (pos ? erv[e] : e2v[e]);
          bool keep = (av[e] != 0) || ((jl + e) == rowm[m]);   // adj + eye
          wv[e] = keep ? wx : 0.0f;
        }
      }
      #pragma unroll
      for (int e = 0; e < 8; ++e) z[m] += wv[e];
      union { sh8 s; int i[4]; } fa;          // A-layout: elem e <-> k = q*8+e
      fa.i[0] = pack2bf(wv[0], wv[1]);
      fa.i[1] = pack2bf(wv[2], wv[3]);
      fa.i[2] = pack2bf(wv[4], wv[5]);
      fa.i[3] = pack2bf(wv[6], wv[7]);
      #pragma unroll
      for (int d = 0; d < 4; ++d)
        acc[m][d] = __builtin_amdgcn_mfma_f32_16x16x32_bf16(fa.s, bf[d], acc[m][d], 0, 0, 0);
    }

    #pragma unroll
    for (int m = 0; m < 4; ++m){ ca[m][0] = na[m][0]; ca[m][1] = na[m][1]; }
  }

  // denominator partials: reduce across quads (lanes r0, r0+16, r0+32, r0+48)
  #pragma unroll
  for (int m = 0; m < 4; ++m){
    z[m] += __shfl_xor(z[m], 16);
    z[m] += __shfl_xor(z[m], 32);
  }
  if (lane < 16){
    #pragma unroll
    for (int m = 0; m < 4; ++m)
      zpart[(jq*4 + h)*N + i0 + m*16 + r0] = z[m];
  }

  // numerator partials: C layout col=r0, row=q*4+reg
  float* pp = part + (size_t)jq*N*HD + h*64 + r0;
  #pragma unroll
  for (int m = 0; m < 4; ++m)
    #pragma unroll
    for (int d = 0; d < 4; ++d)
      #pragma unroll
      for (int reg = 0; reg < 4; ++reg)
        pp[(size_t)(i0 + m*16 + q*4 + reg)*HD + d*16] = acc[m][d][reg];
}

// ---------------- K3: combine 4 j-quarter partials, divide, write out --------------
__global__ void k_out(const float* __restrict__ part, const float* __restrict__ zpart,
                      float* __restrict__ out)
{
  const int idx = blockIdx.x*256 + threadIdx.x;
  const int i = idx >> 8;
  const int h = (idx & 255) >> 6;
  float num = part[idx] + part[idx + N*HD] + part[idx + 2*N*HD] + part[idx + 3*N*HD];
  float zz = zpart[h*N + i] + zpart[(4 + h)*N + i] + zpart[(8 + h)*N + i] + zpart[(12 + h)*N + i];
  out[idx] = num / zz;
}

extern "C" void kernel_launch(void* const* d_in, const int* in_sizes, int n_in,
                              void* d_out, int out_size, void* d_ws, size_t ws_size,
                              hipStream_t stream) {
  const float* x   = (const float*)d_in[0];
  const int*   adj = (const int*)d_in[1];
  const float* W   = (const float*)d_in[2];
  const float* a_l = (const float*)d_in[3];
  const float* a_r = (const float*)d_in[4];
  float* out = (float*)d_out;

  char* ws = (char*)d_ws;
  __hip_bfloat16* Wt = (__hip_bfloat16*)ws;                           // 131072 B
  __hip_bfloat16* ht = (__hip_bfloat16*)(ws + 131072);                // 4 MB
  float* sc    = (float*)(ws + 131072 + 4194304);                     // 768 KB (6 arrays)
  float* part  = (float*)(ws + 131072 + 4194304 + 786432);            // 32 MB
  float* zpart = (float*)(ws + 131072 + 4194304 + 786432 + 33554432); // 512 KB

  k_wt  <<<dim3(16,16), dim3(16,16), 0, stream>>>(W, Wt);
  k_h   <<<256, 256, 0, stream>>>(x, Wt, a_l, a_r, ht, sc);
  k_attn<<<512, 256, 0, stream>>>(adj, ht, sc, part, zpart);
  k_out <<<N*HD/256, 256, 0, stream>>>(part, zpart, out);
}

// Round 2
// 542.538 us; speedup vs baseline: 1.1357x; 1.1357x over previous
//
#include <hip/hip_runtime.h>
#include <hip/hip_bf16.h>

#define N 8192
#define FIN 256
#define HD 256
#define LEAKY 0.2f

typedef short sh8 __attribute__((ext_vector_type(8)));   // bf16x8 MFMA fragment
typedef float f32x4 __attribute__((ext_vector_type(4)));
typedef int   i32x4 __attribute__((ext_vector_type(4)));

__device__ __forceinline__ int pack2bf(float a, float b){
  __hip_bfloat162 t = __float22bfloat162_rn(make_float2(a, b));
  union { __hip_bfloat162 h; int i; } u;
  u.h = t;
  return u.i;
}

__device__ __forceinline__ unsigned bf16hi_rne(float v){
  unsigned u = __float_as_uint(v);
  u += 0x7FFFu + ((u >> 16) & 1u);
  return u >> 16;
}

// ---------------- K0: W (256x256 f32, [k][c]) -> Wt (bf16, [c][k]) ----------------
__global__ void k_wt(const float* __restrict__ W, __hip_bfloat16* __restrict__ Wt){
  __shared__ float t[16][17];
  int tx = threadIdx.x, ty = threadIdx.y;
  int bx = blockIdx.x*16, by = blockIdx.y*16;
  t[ty][tx] = W[(by+ty)*HD + (bx+tx)];
  __syncthreads();
  Wt[(bx+ty)*FIN + (by+tx)] = __float2bfloat16(t[tx][ty]);
}

// ---------------- K1: h_t[c][n] = sum_k W[k][c] * x[n][k]  (bf16 out) --------------
// Fused epilogue: El=exp(sl), El2=exp(0.2*sl) (fp32, i-side) and EE[h][j] =
// packed (bf16(exp(sr)) | bf16(exp(0.2*sr))<<16) (j-side).
__global__ __launch_bounds__(256, 2) void k_h(
    const float* __restrict__ x, const __hip_bfloat16* __restrict__ Wt,
    const float* __restrict__ a_l, const float* __restrict__ a_r,
    __hip_bfloat16* __restrict__ ht, float* __restrict__ El, float* __restrict__ El2,
    unsigned* __restrict__ ee)
{
  const int lane = threadIdx.x & 63;
  const int w = threadIdx.x >> 6;      // c-group == head
  const int r0 = lane & 15, q = lane >> 4;
  const int c0 = w*64;
  const int n0 = blockIdx.x*32;

  f32x4 acc[4][2];
  #pragma unroll
  for (int m = 0; m < 4; ++m)
    #pragma unroll
    for (int nt = 0; nt < 2; ++nt)
      acc[m][nt] = (f32x4){0.f, 0.f, 0.f, 0.f};

  for (int kb = 0; kb < 8; ++kb){
    const int k = kb*32 + q*8;
    sh8 af[4];
    #pragma unroll
    for (int m = 0; m < 4; ++m)
      af[m] = *(const sh8*)(Wt + (c0 + m*16 + r0)*FIN + k);
    #pragma unroll
    for (int nt = 0; nt < 2; ++nt){
      const float* xp = x + (n0 + nt*16 + r0)*FIN + k;
      f32x4 xl = *(const f32x4*)xp;
      f32x4 xh = *(const f32x4*)(xp + 4);
      union { sh8 s; int i[4]; } bx;
      bx.i[0] = pack2bf(xl[0], xl[1]);
      bx.i[1] = pack2bf(xl[2], xl[3]);
      bx.i[2] = pack2bf(xh[0], xh[1]);
      bx.i[3] = pack2bf(xh[2], xh[3]);
      #pragma unroll
      for (int m = 0; m < 4; ++m)
        acc[m][nt] = __builtin_amdgcn_mfma_f32_16x16x32_bf16(af[m], bx.s, acc[m][nt], 0, 0, 0);
    }
  }

  // epilogue: store h_t (bf16) + fused scores
  float pl[2] = {0.f, 0.f}, pr[2] = {0.f, 0.f};
  #pragma unroll
  for (int m = 0; m < 4; ++m){
    #pragma unroll
    for (int reg = 0; reg < 4; ++reg){
      const int c = c0 + m*16 + q*4 + reg;      // C row = q*4+reg
      const float alv = a_l[c], arv = a_r[c];
      #pragma unroll
      for (int nt = 0; nt < 2; ++nt){
        float v = acc[m][nt][reg];
        ht[(size_t)c*N + (n0 + nt*16 + r0)] = __float2bfloat16(v);  // C col = r0
        pl[nt] += v*alv;
        pr[nt] += v*arv;
      }
    }
  }
  #pragma unroll
  for (int nt = 0; nt < 2; ++nt){
    pl[nt] += __shfl_xor(pl[nt], 16); pl[nt] += __shfl_xor(pl[nt], 32);
    pr[nt] += __shfl_xor(pr[nt], 16); pr[nt] += __shfl_xor(pr[nt], 32);
  }
  if (lane < 16){
    #pragma unroll
    for (int nt = 0; nt < 2; ++nt){
      const int n = n0 + nt*16 + r0;
      const float l = pl[nt], r = pr[nt];
      El [w*N + n] = __expf(l);
      El2[w*N + n] = __expf(LEAKY*l);
      float er  = __expf(r);
      float er2 = __expf(LEAKY*r);
      ee[w*N + n] = bf16hi_rne(er) | (bf16hi_rne(er2) << 16);
    }
  }
}

// ---------------- K_bits: adj (N*N int32) -> bitmask u64[row][N/64], eye OR'd in ---
__global__ __launch_bounds__(256) void k_bits(const int* __restrict__ adj,
                                              unsigned long long* __restrict__ bits)
{
  const int lane = threadIdx.x & 63;
  const int wid = (blockIdx.x*256 + threadIdx.x) >> 6;   // global wave id
  const int nw = (gridDim.x*256) >> 6;
  const int total = (N/64)*N;                            // row-major: idx = r*128 + c
  for (int idx = wid; idx < total; idx += nw){
    const int r = idx >> 7, c = idx & 127;
    int av = __builtin_nontemporal_load(adj + (size_t)r*N + c*64 + lane);
    unsigned long long b = __ballot(av != 0);
    if (c == (r >> 6)) b |= 1ull << (r & 63);            // + eye
    if (lane == 0) bits[idx] = b;
  }
}

// ---------------- K2: masked-softmax numerator/denominator partials ----------------
struct Frag {
  unsigned bw[4];
  i32x4 ee2[2];
  sh8 hf[4];
};

__device__ __forceinline__ void ld_frag(Frag& f, int t,
    const unsigned* __restrict__ bp0, const unsigned* __restrict__ bp1,
    const unsigned* __restrict__ bp2, const unsigned* __restrict__ bp3,
    const unsigned* __restrict__ eeh, const __hip_bfloat16* __restrict__ htb,
    int joff)
{
  const int jl = joff + t*32;
  f.bw[0] = bp0[t]; f.bw[1] = bp1[t]; f.bw[2] = bp2[t]; f.bw[3] = bp3[t];
  f.ee2[0] = *(const i32x4*)(eeh + jl);
  f.ee2[1] = *(const i32x4*)(eeh + jl + 4);
  #pragma unroll
  for (int d = 0; d < 4; ++d)
    f.hf[d] = *(const sh8*)(htb + (size_t)(d*16)*N + jl);
}

__device__ __forceinline__ void body(const Frag& f, const float* el, const float* el2,
    int q, const sh8& ones, f32x4 acc[4][4], f32x4 accz[4])
{
  float er[8], er2[8];
  #pragma unroll
  for (int e = 0; e < 8; ++e){
    unsigned u = (e < 4) ? (unsigned)f.ee2[0][e] : (unsigned)f.ee2[1][e-4];
    er[e]  = __uint_as_float(u << 16);
    er2[e] = __uint_as_float(u & 0xFFFF0000u);
  }
  #pragma unroll
  for (int m = 0; m < 4; ++m){
    const unsigned sw = f.bw[m] >> (q*8);
    unsigned fi[4];
    #pragma unroll
    for (int p = 0; p < 4; ++p){
      float w0 = fmaxf(el[m]*er[2*p],   el2[m]*er2[2*p]);
      float w1 = fmaxf(el[m]*er[2*p+1], el2[m]*er2[2*p+1]);
      w0 = (sw & (1u << (2*p)))   ? w0 : 0.0f;
      w1 = (sw & (1u << (2*p+1))) ? w1 : 0.0f;
      // RTZ bf16x2 pack in one v_perm_b32 (z-MFMA sums the SAME truncated values,
      // so the truncation bias cancels in num/z)
      fi[p] = __builtin_amdgcn_perm(__float_as_uint(w1), __float_as_uint(w0), 0x07060302u);
    }
    union { sh8 s; unsigned u[4]; } fa;
    fa.u[0]=fi[0]; fa.u[1]=fi[1]; fa.u[2]=fi[2]; fa.u[3]=fi[3];
    #pragma unroll
    for (int d = 0; d < 4; ++d)
      acc[m][d] = __builtin_amdgcn_mfma_f32_16x16x32_bf16(fa.s, f.hf[d], acc[m][d], 0, 0, 0);
    accz[m] = __builtin_amdgcn_mfma_f32_16x16x32_bf16(fa.s, ones, accz[m], 0, 0, 0);
  }
}

// grid 512: block b -> i-tile (b>>2)*64, j-quarter (b&3)*2048. 4 waves = 4 heads.
__global__ __launch_bounds__(256, 2) void k_attn(
    const unsigned* __restrict__ bits32, const __hip_bfloat16* __restrict__ ht,
    const float* __restrict__ El, const float* __restrict__ El2,
    const unsigned* __restrict__ ee, float* __restrict__ part, float* __restrict__ zpart)
{
  const int b = blockIdx.x;
  const int iblk = b >> 2, jq = b & 3;
  const int lane = threadIdx.x & 63;
  const int h = threadIdx.x >> 6;
  const int r0 = lane & 15, q = lane >> 4;
  const int i0 = iblk * 64;
  const int jbase = jq * 2048;
  const int joff = jbase + q*8;

  float el[4], el2[4];
  const unsigned* bp[4];
  #pragma unroll
  for (int m = 0; m < 4; ++m){
    const int row = i0 + m*16 + r0;
    el[m]  = El [h*N + row];
    el2[m] = El2[h*N + row];
    bp[m] = bits32 + (size_t)row*(N/32) + (jbase >> 5);
  }

  // ones B-frag: B[k][0] = 1.0 for all k -> z = row-sums land in C col 0
  union { sh8 s; int i[4]; } onef;
  {
    int v = (r0 == 0) ? 0x3F803F80 : 0;
    onef.i[0]=v; onef.i[1]=v; onef.i[2]=v; onef.i[3]=v;
  }

  f32x4 acc[4][4];
  f32x4 accz[4];
  #pragma unroll
  for (int m = 0; m < 4; ++m){
    accz[m] = (f32x4){0.f,0.f,0.f,0.f};
    #pragma unroll
    for (int d = 0; d < 4; ++d)
      acc[m][d] = (f32x4){0.f,0.f,0.f,0.f};
  }

  const unsigned* eeh = ee + h*N;
  const __hip_bfloat16* htb = ht + (size_t)(h*64 + r0)*N;

  Frag fA, fB;
  ld_frag(fA, 0, bp[0], bp[1], bp[2], bp[3], eeh, htb, joff);

  for (int t = 0; t < 64; t += 2){
    ld_frag(fB, t+1, bp[0], bp[1], bp[2], bp[3], eeh, htb, joff);
    body(fA, el, el2, q, onef.s, acc, accz);
    const int tn = (t+2 < 64) ? t+2 : 0;      // last prefetch harmless (unused)
    ld_frag(fA, tn, bp[0], bp[1], bp[2], bp[3], eeh, htb, joff);
    body(fB, el, el2, q, onef.s, acc, accz);
  }

  // z partials: col 0 of accz -> lanes with r0==0, row = q*4+reg
  if (r0 == 0){
    #pragma unroll
    for (int m = 0; m < 4; ++m)
      #pragma unroll
      for (int reg = 0; reg < 4; ++reg)
        zpart[(jq*4 + h)*N + i0 + m*16 + q*4 + reg] = accz[m][reg];
  }

  // numerator partials: C layout col=r0, row=q*4+reg
  float* pp = part + (size_t)jq*N*HD + h*64 + r0;
  #pragma unroll
  for (int m = 0; m < 4; ++m)
    #pragma unroll
    for (int d = 0; d < 4; ++d)
      #pragma unroll
      for (int reg = 0; reg < 4; ++reg)
        pp[(size_t)(i0 + m*16 + q*4 + reg)*HD + d*16] = acc[m][d][reg];
}

// ---------------- K3: combine 4 j-quarter partials, divide, write out --------------
__global__ void k_out(const float* __restrict__ part, const float* __restrict__ zpart,
                      float* __restrict__ out)
{
  const int t4 = (blockIdx.x*256 + threadIdx.x) * 4;   // 4 consecutive c (same head)
  const int i = t4 >> 8;
  const int h = (t4 & 255) >> 6;
  f32x4 a = *(const f32x4*)(part + t4);
  f32x4 bq = *(const f32x4*)(part + (size_t)N*HD + t4);
  f32x4 c = *(const f32x4*)(part + 2*(size_t)N*HD + t4);
  f32x4 d = *(const f32x4*)(part + 3*(size_t)N*HD + t4);
  float zz = zpart[h*N + i] + zpart[(4 + h)*N + i] + zpart[(8 + h)*N + i] + zpart[(12 + h)*N + i];
  f32x4 s = (a + bq + c + d) / zz;
  *(f32x4*)(out + t4) = s;
}

extern "C" void kernel_launch(void* const* d_in, const int* in_sizes, int n_in,
                              void* d_out, int out_size, void* d_ws, size_t ws_size,
                              hipStream_t stream) {
  const float* x   = (const float*)d_in[0];
  const int*   adj = (const int*)d_in[1];
  const float* W   = (const float*)d_in[2];
  const float* a_l = (const float*)d_in[3];
  const float* a_r = (const float*)d_in[4];
  float* out = (float*)d_out;

  char* ws = (char*)d_ws;
  __hip_bfloat16* Wt = (__hip_bfloat16*)ws;                     // 128 KB
  __hip_bfloat16* ht = (__hip_bfloat16*)(ws + 131072);          // 4 MB
  float*    El   = (float*)   (ws + 4325376);                   // 128 KB
  float*    El2  = (float*)   (ws + 4456448);                   // 128 KB
  unsigned* ee   = (unsigned*)(ws + 4587520);                   // 128 KB
  unsigned long long* bits = (unsigned long long*)(ws + 4718592); // 8 MB
  float*    part = (float*)   (ws + 13107200);                  // 32 MB
  float*    zpart= (float*)   (ws + 46661632);                  // 512 KB

  k_wt  <<<dim3(16,16), dim3(16,16), 0, stream>>>(W, Wt);
  k_h   <<<256, 256, 0, stream>>>(x, Wt, a_l, a_r, ht, El, El2, ee);
  k_bits<<<4096, 256, 0, stream>>>(adj, bits);
  k_attn<<<512, 256, 0, stream>>>((const unsigned*)bits, ht, El, El2, ee, part, zpart);
  k_out <<<N*HD/1024, 256, 0, stream>>>(part, zpart, out);
}